// Round 17
// baseline (100.491 us; speedup 1.0000x reference)
//
#include <hip/hip_runtime.h>
#include <hip/hip_bf16.h>
#include <cstdint>

#define B_ 4096
#define D_ 256
#define M_ 60
#define NT_ 32          // 128-tiles per dimension
#define NBLK 528        // NT_*(NT_+1)/2 upper-triangle tiles
#define BM 128

typedef unsigned long long u64;
typedef short bf16x8 __attribute__((ext_vector_type(8)));   // 8 bf16 = 4 VGPRs
typedef float f32x4 __attribute__((ext_vector_type(4)));

__device__ __forceinline__ unsigned short f2bf(float x) {
    __hip_bfloat16 b = __float2bfloat16(x);
    return __builtin_bit_cast(unsigned short, b);
}

// ---------- prep: bf16 cast of raw rep, inv-norm*sqrt(10), code masks (coalesced, once) ----------
__global__ __launch_bounds__(256) void prep_kernel(
    const float* __restrict__ rep, const int* __restrict__ codes,
    unsigned short* __restrict__ nb, float* __restrict__ invs,
    u64* __restrict__ lo, u64* __restrict__ hi, int* __restrict__ cnt) {
    const int w = threadIdx.x >> 6;
    const int lane = threadIdx.x & 63;
    const int row = blockIdx.x * 4 + w;

    float4 v = ((const float4*)(rep + (size_t)row * D_))[lane];
    float ss = v.x * v.x + v.y * v.y + v.z * v.z + v.w * v.w;
#pragma unroll
    for (int off = 32; off > 0; off >>= 1) ss += __shfl_down(ss, off);
    ss = __shfl(ss, 0);

    // store RAW bf16 (normalization folded into epilogue scale)
    ushort4 o;
    o.x = f2bf(v.x); o.y = f2bf(v.y); o.z = f2bf(v.z); o.w = f2bf(v.w);
    ((ushort4*)(nb + (size_t)row * D_))[lane] = o;

    // code membership mask via wave-OR reduction
    u64 l = 0, h = 0;
    if (lane < M_) {
        int c = codes[row * M_ + lane];
        if (c < 64) l = 1ull << c;
        else        h = 1ull << (c - 64);
    }
#pragma unroll
    for (int off = 32; off > 0; off >>= 1) {
        l |= __shfl_down(l, off);
        h |= __shfl_down(h, off);
    }
    if (lane == 0) {
        invs[row] = (1.0f / sqrtf(ss)) * 3.16227766016838f;  // inv_norm * sqrt(1/T)
        lo[row] = l; hi[row] = h;
        cnt[row] = __popcll(l) + __popcll(h);
    }
}

// ---------- fused: 128x128 tiles, 4 waves, MFMA DIRECT FROM GLOBAL (no LDS, no barriers) ----------
// R12 post-mortem: Nb is 2 MiB -> L2-resident on every XCD. Staging (global_load_lds +
// vmcnt(0) drain + 2 barriers/K-step + 384 ds_read/block) is pure overhead when the source
// is an L2 hit; four different staging structures all pinned at ~23-30us. This kernel loads
// MFMA fragments straight to VGPRs: lane(l15,quad) reads Nb[row*512 + s*64 + quad*16] as
// dwordx4 -> each 16-lane quad covers 16 full 64B lines (no over-fetch). Zero sync in the
// K-loop; 64 independent loads pipeline against 128 MFMAs. Wave w owns a 64x64 quadrant
// (wr=w>>1, wc=w&1), acc[4][4] f32x4 = 64 VGPR. Same verified epilogue math as R9/R12.
__global__ __launch_bounds__(256) void fused_kernel(
    const unsigned short* __restrict__ Nb, const float* __restrict__ invs,
    const u64* __restrict__ lo, const u64* __restrict__ hi, const int* __restrict__ cnt,
    double* __restrict__ partials /* NBLK x 8 doubles (64B stride) */) {
    __shared__ float redT[4], redPe[4], redPs[4];
    __shared__ int redC[4];

    const int tid = threadIdx.x;
    const int lane = tid & 63;
    const int w = tid >> 6;          // 0..3
    const int wr = w >> 1, wc = w & 1;
    const int quad = lane >> 4;
    const int l15 = lane & 15;

    // block -> (bi, bj) with bj >= bi
    int q = blockIdx.x, bi = 0;
    while (q >= NT_ - bi) { q -= NT_ - bi; bi++; }
    const int bj = bi + q;
    const int rowA = bi * BM, rowB = bj * BM;

    // column-side epilogue metadata early (hides under the first fragment loads)
    u64 jl[4], jh[4]; int jc[4]; float ibv[4]; int cglob[4];
#pragma unroll
    for (int j = 0; j < 4; j++) {
        int cg = rowB + wc * 64 + j * 16 + l15;
        cglob[j] = cg; jl[j] = lo[cg]; jh[j] = hi[cg]; jc[j] = cnt[cg]; ibv[j] = invs[cg];
    }

    // ---- K-loop: 8 steps of K=32, fragments straight from global (L2-hit) ----
    const char* baseA = (const char*)Nb + (size_t)(rowA + wr * 64) * 512;
    const char* baseB = (const char*)Nb + (size_t)(rowB + wc * 64) * 512;
    f32x4 accf[4][4] = {};
#pragma unroll
    for (int s = 0; s < 8; s++) {
        const int koff = s * 64 + quad * 16;   // quad q supplies k = q*8..q*8+8 of this K=32 block
        bf16x8 a[4], b[4];
#pragma unroll
        for (int i = 0; i < 4; i++)
            a[i] = *(const bf16x8*)(baseA + (size_t)(i * 16 + l15) * 512 + koff);
#pragma unroll
        for (int j = 0; j < 4; j++)
            b[j] = *(const bf16x8*)(baseB + (size_t)(j * 16 + l15) * 512 + koff);
#pragma unroll
        for (int i = 0; i < 4; i++)
#pragma unroll
            for (int j = 0; j < 4; j++)
                accf[i][j] = __builtin_amdgcn_mfma_f32_16x16x32_bf16(a[i], b[j], accf[i][j], 0, 0, 0);
    }

    // ---------- epilogue ----------
    // C/D layout (16x16): col = lane&15 (B side), row = quad*4 + reg (A side)
    float t_sum = 0.0f, p_exp = 0.0f, p_s = 0.0f;
    int p_cnt = 0;
#pragma unroll
    for (int i = 0; i < 4; i++) {
        int rbase = rowA + wr * 64 + i * 16 + quad * 4;
        u64 al[4], ah[4]; int ac[4]; float ia[4];
#pragma unroll
        for (int r = 0; r < 4; r++) {
            al[r] = lo[rbase + r]; ah[r] = hi[rbase + r];
            ac[r] = cnt[rbase + r]; ia[r] = invs[rbase + r];
        }
#pragma unroll
        for (int j = 0; j < 4; j++) {
#pragma unroll
            for (int r = 0; r < 4; r++) {
                float s = accf[i][j][r] * ia[r] * ibv[j];   // dot * inv_i*inv_j*10
                float es = __expf(s);
                t_sum += es;
                int inter = __popcll(al[r] & jl[j]) + __popcll(ah[r] & jh[j]);
                int uni = ac[r] + jc[j] - inter;
                if ((10 * inter > 3 * uni) && (rbase + r != cglob[j])) {
                    p_exp += es; p_s += s; p_cnt++;
                }
            }
        }
    }

    // per-wave reduction, LDS combine, ONE uncontended store per block
#pragma unroll
    for (int off = 32; off > 0; off >>= 1) {
        t_sum += __shfl_down(t_sum, off);
        p_exp += __shfl_down(p_exp, off);
        p_s   += __shfl_down(p_s, off);
        p_cnt += __shfl_down(p_cnt, off);
    }
    if (lane == 0) { redT[w] = t_sum; redPe[w] = p_exp; redPs[w] = p_s; redC[w] = p_cnt; }
    __syncthreads();
    if (tid == 0) {
        double T = 0, Pe = 0, Ps = 0;
        long long C = 0;
        for (int i = 0; i < 4; i++) {
            T += (double)redT[i]; Pe += (double)redPe[i];
            Ps += (double)redPs[i]; C += redC[i];
        }
        double scale = (bi == bj) ? 1.0 : 2.0;   // symmetry: off-diagonal counts twice
        double* dst = partials + (size_t)blockIdx.x * 8;
        dst[0] = T * scale;
        dst[1] = Pe * scale;
        dst[2] = Ps * scale;
        dst[3] = (double)C * scale;
    }
}

// ---------- finalize: reduce 528 partials, compute loss ----------
__global__ __launch_bounds__(256) void finalize_kernel(
    const double* __restrict__ partials, float* __restrict__ out) {
    const int tid = threadIdx.x;
    const int lane = tid & 63;
    const int w = tid >> 6;
    double T = 0, Pe = 0, Ps = 0, C = 0;
    for (int i = tid; i < NBLK; i += 256) {
        const double* src = partials + (size_t)i * 8;
        T += src[0]; Pe += src[1]; Ps += src[2]; C += src[3];
    }
#pragma unroll
    for (int off = 32; off > 0; off >>= 1) {
        T += __shfl_down(T, off);
        Pe += __shfl_down(Pe, off);
        Ps += __shfl_down(Ps, off);
        C += __shfl_down(C, off);
    }
    __shared__ double redT[4], redPe[4], redPs[4], redC[4];
    if (lane == 0) { redT[w] = T; redPe[w] = Pe; redPs[w] = Ps; redC[w] = C; }
    __syncthreads();
    if (tid == 0) {
        double Tt = 0, Pet = 0, Pst = 0, n = 0;
        for (int i = 0; i < 4; i++) { Tt += redT[i]; Pet += redPe[i]; Pst += redPs[i]; n += redC[i]; }
        double neg = Tt - Pet;   // negatives incl. diagonal
        double loss = (n > 0.0) ? log(neg) + (Pet / neg - Pst) / n : 0.0;
        out[0] = (float)loss;
    }
}

extern "C" void kernel_launch(void* const* d_in, const int* in_sizes, int n_in,
                              void* d_out, int out_size, void* d_ws, size_t ws_size,
                              hipStream_t stream) {
    const float* rep = (const float*)d_in[0];
    const int* codes = (const int*)d_in[1];
    // d_in[2] = labels, unused by the reference computation

    // workspace layout
    unsigned short* nb = (unsigned short*)d_ws;                // 2 MiB raw bf16
    char* p = (char*)d_ws + (size_t)B_ * D_ * 2;
    float* invs = (float*)p;                                   // 16 KiB
    u64* lo = (u64*)(invs + B_);                               // 32 KiB
    u64* hi = lo + B_;                                         // 32 KiB
    int* cnt = (int*)(hi + B_);                                // 16 KiB
    double* partials = (double*)(cnt + B_);                    // 528 x 8 doubles

    float* out = (float*)d_out;

    prep_kernel<<<B_ / 4, 256, 0, stream>>>(rep, codes, nb, invs, lo, hi, cnt);
    fused_kernel<<<NBLK, 256, 0, stream>>>(nb, invs, lo, hi, cnt, partials);
    finalize_kernel<<<1, 256, 0, stream>>>(partials, out);
}

// Round 18
// 81.631 us; speedup vs baseline: 1.2310x; 1.2310x over previous
//
#include <hip/hip_runtime.h>
#include <hip/hip_bf16.h>
#include <cstdint>

#define B_ 4096
#define D_ 256
#define M_ 60
#define NT_ 32          // 128-tiles per dimension
#define NBLK 528        // NT_*(NT_+1)/2 upper-triangle tiles; 528 = 8 XCDs * 66 (bijective swizzle)
#define BM 128
#define BK 64           // bf16 elements per K-step (128 bytes/row)

typedef unsigned long long u64;
typedef short bf16x8 __attribute__((ext_vector_type(8)));   // 8 bf16 = 4 VGPRs
typedef float f32x4 __attribute__((ext_vector_type(4)));

__device__ __forceinline__ unsigned short f2bf(float x) {
    __hip_bfloat16 b = __float2bfloat16(x);
    return __builtin_bit_cast(unsigned short, b);
}

// ---------- prep: bf16 cast of raw rep, inv-norm*sqrt(10), code masks (coalesced, once) ----------
__global__ __launch_bounds__(256) void prep_kernel(
    const float* __restrict__ rep, const int* __restrict__ codes,
    unsigned short* __restrict__ nb, float* __restrict__ invs,
    u64* __restrict__ lo, u64* __restrict__ hi, int* __restrict__ cnt) {
    const int w = threadIdx.x >> 6;
    const int lane = threadIdx.x & 63;
    const int row = blockIdx.x * 4 + w;

    float4 v = ((const float4*)(rep + (size_t)row * D_))[lane];
    float ss = v.x * v.x + v.y * v.y + v.z * v.z + v.w * v.w;
#pragma unroll
    for (int off = 32; off > 0; off >>= 1) ss += __shfl_down(ss, off);
    ss = __shfl(ss, 0);

    // store RAW bf16 (normalization folded into epilogue scale)
    ushort4 o;
    o.x = f2bf(v.x); o.y = f2bf(v.y); o.z = f2bf(v.z); o.w = f2bf(v.w);
    ((ushort4*)(nb + (size_t)row * D_))[lane] = o;

    // code membership mask via wave-OR reduction
    u64 l = 0, h = 0;
    if (lane < M_) {
        int c = codes[row * M_ + lane];
        if (c < 64) l = 1ull << c;
        else        h = 1ull << (c - 64);
    }
#pragma unroll
    for (int off = 32; off > 0; off >>= 1) {
        l |= __shfl_down(l, off);
        h |= __shfl_down(h, off);
    }
    if (lane == 0) {
        invs[row] = (1.0f / sqrtf(ss)) * 3.16227766016838f;  // inv_norm * sqrt(1/T)
        lo[row] = l; hi[row] = h;
        cnt[row] = __popcll(l) + __popcll(h);
    }
}

// ---------- fused: 128x128 tiles, 512 threads, 2-phase dbuf with COUNTED vmcnt (T4) ----------
// R17: direct-from-global regressed (42us vs 23) -> staging stays. R12's loop drained
// vmcnt(0) at every __syncthreads, killing stage(t+1)'s overlap (T4 defect, m218/m233).
// This version: per step {STAGE(t+1); s_waitcnt vmcnt(4) [stage(t) done, stage(t+1) in
// flight]; s_barrier; compute(t); s_barrier}. Overwrite-safety: buf[nxt] last read at
// step t-1 which ended with a barrier. All else identical to R12 (81.0us baseline).
__global__ __launch_bounds__(512, 4) void fused_kernel(
    const unsigned short* __restrict__ Nb, const float* __restrict__ invs,
    const u64* __restrict__ lo, const u64* __restrict__ hi, const int* __restrict__ cnt,
    double* __restrict__ partials /* NBLK x 8 doubles (64B stride) */) {
    __shared__ __attribute__((aligned(16))) char AsB[2 * BM * BK * 2];   // 32 KB (2 bufs)
    __shared__ __attribute__((aligned(16))) char BsB[2 * BM * BK * 2];   // 32 KB
    __shared__ u64 mLo[256], mHi[256];       // [0..127]=A rows, [128..255]=B cols
    __shared__ int mCnt[256];
    __shared__ float mInv[256];
    __shared__ float redT[8], redPe[8], redPs[8];
    __shared__ int redC[8];

    const int tid = threadIdx.x;
    const int lane = tid & 63;
    const int w = tid >> 6;          // 0..7
    const int wr = w >> 2, wc = w & 3;   // wave -> 64x32 sub-tile
    const int quad = lane >> 4;
    const int l15 = lane & 15;
    const int l7 = lane & 7;

    // XCD-aware bijective swizzle (528 = 8*66), then -> (bi, bj) with bj >= bi
    const int bid = blockIdx.x;
    const int swz = (bid & 7) * 66 + (bid >> 3);
    int q = swz, bi = 0;
    while (q >= NT_ - bi) { q -= NT_ - bi; bi++; }
    const int bj = bi + q;
    const int rowA = bi * BM, rowB = bj * BM;

    // stage one K-step (16 KB per operand = 16 regions x 1024 B each); 8 waves x 2 regions
    // -> 4 global_load_lds per thread (vmcnt accounting relies on this)
    auto STAGE = [&](int t, int buf) {
        const int k0 = t * BK;
#pragma unroll
        for (int it = 0; it < 2; it++) {
            int region = it * 8 + w;          // 0..15
            int P = region * 64 + lane;       // 0..1023
            int row = P >> 3;
            int c = (P & 7) ^ (row & 7);
            const unsigned short* gA = Nb + (size_t)(rowA + row) * D_ + k0 + c * 8;
            const unsigned short* gB = Nb + (size_t)(rowB + row) * D_ + k0 + c * 8;
            __builtin_amdgcn_global_load_lds(
                (const __attribute__((address_space(1))) void*)gA,
                (__attribute__((address_space(3))) void*)(AsB + buf * 16384 + region * 1024), 16, 0, 0);
            __builtin_amdgcn_global_load_lds(
                (const __attribute__((address_space(1))) void*)gB,
                (__attribute__((address_space(3))) void*)(BsB + buf * 16384 + region * 1024), 16, 0, 0);
        }
    };

    // prologue: stage step 0, metadata->LDS, full drain (stage(0) must be complete anyway)
    STAGE(0, 0);
    if (tid < 128) {
        int g = rowA + tid;
        mLo[tid] = lo[g]; mHi[tid] = hi[g]; mCnt[tid] = cnt[g]; mInv[tid] = invs[g];
    } else if (tid < 256) {
        int t2 = tid - 128;
        int g = rowB + t2;
        mLo[128 + t2] = lo[g]; mHi[128 + t2] = hi[g]; mCnt[128 + t2] = cnt[g]; mInv[128 + t2] = invs[g];
    }
    __syncthreads();   // drains vmcnt (tiles+meta) + lgkmcnt (meta ds_writes)

    // ---- counted-vmcnt 2-phase K-loop: 4 steps of BK=64 ----
    f32x4 accf[4][2] = {};
    int cur = 0;
#pragma unroll
    for (int t = 0; t < 4; t++) {
        if (t < 3) {
            STAGE(t + 1, cur ^ 1);                 // buf[cur^1] last read at t-1 (barrier'd)
            // wait for MY stage(t) loads (4 older); stage(t+1)'s 4 remain in flight
            asm volatile("s_waitcnt vmcnt(4)" ::: "memory");
        } else {
            asm volatile("s_waitcnt vmcnt(0)" ::: "memory");   // drain stage(3)
        }
        __builtin_amdgcn_sched_barrier(0);         // rule 18: pin ds_reads after the wait
        __builtin_amdgcn_s_barrier();              // ⇒ ALL waves' stage(t) complete
#pragma unroll
        for (int kk = 0; kk < 2; kk++) {
            const int pc = (kk * 4 + quad) ^ l7;   // swizzled 16B chunk
            bf16x8 a[4], b[2];
#pragma unroll
            for (int i = 0; i < 4; i++) {
                int rA = wr * 64 + i * 16 + l15;
                a[i] = *(const bf16x8*)(AsB + cur * 16384 + rA * 128 + pc * 16);
            }
#pragma unroll
            for (int j = 0; j < 2; j++) {
                int rB = wc * 32 + j * 16 + l15;
                b[j] = *(const bf16x8*)(BsB + cur * 16384 + rB * 128 + pc * 16);
            }
#pragma unroll
            for (int i = 0; i < 4; i++)
#pragma unroll
                for (int j = 0; j < 2; j++)
                    accf[i][j] = __builtin_amdgcn_mfma_f32_16x16x32_bf16(a[i], b[j], accf[i][j], 0, 0, 0);
        }
        // all my ds_reads of buf[cur] retired (results consumed by MFMA); wave-sync so
        // no wave's next-step STAGE overwrites a buffer another wave still reads
        asm volatile("s_waitcnt lgkmcnt(0)" ::: "memory");
        __builtin_amdgcn_s_barrier();
        cur ^= 1;
    }

    // ---------- epilogue ----------
    // C/D layout (16x16): col = lane&15, row = quad*4 + reg
    // col-side metadata hoisted once (2 j-tiles per wave)
    u64 jl[2], jh[2]; int jc[2]; float ibv[2]; int cglob[2];
#pragma unroll
    for (int j = 0; j < 2; j++) {
        int cloc = wc * 32 + j * 16 + l15;
        jl[j] = mLo[128 + cloc]; jh[j] = mHi[128 + cloc];
        jc[j] = mCnt[128 + cloc]; ibv[j] = mInv[128 + cloc];
        cglob[j] = rowB + cloc;
    }

    float t_sum = 0.0f, p_exp = 0.0f, p_s = 0.0f;
    int p_cnt = 0;
#pragma unroll
    for (int i = 0; i < 4; i++) {
        int rloc = wr * 64 + i * 16 + quad * 4;
        u64 al[4], ah[4]; int ac[4]; float ia[4];
#pragma unroll
        for (int r = 0; r < 4; r++) {
            al[r] = mLo[rloc + r]; ah[r] = mHi[rloc + r];
            ac[r] = mCnt[rloc + r]; ia[r] = mInv[rloc + r];
        }
        int rglob = rowA + rloc;
#pragma unroll
        for (int j = 0; j < 2; j++) {
#pragma unroll
            for (int r = 0; r < 4; r++) {
                float s = accf[i][j][r] * ia[r] * ibv[j];   // dot * inv_i*inv_j*10
                float es = __expf(s);
                t_sum += es;
                int inter = __popcll(al[r] & jl[j]) + __popcll(ah[r] & jh[j]);
                int uni = ac[r] + jc[j] - inter;
                if ((10 * inter > 3 * uni) && (rglob + r != cglob[j])) {
                    p_exp += es; p_s += s; p_cnt++;
                }
            }
        }
    }

    // per-wave reduction, LDS combine, ONE uncontended store per block
#pragma unroll
    for (int off = 32; off > 0; off >>= 1) {
        t_sum += __shfl_down(t_sum, off);
        p_exp += __shfl_down(p_exp, off);
        p_s   += __shfl_down(p_s, off);
        p_cnt += __shfl_down(p_cnt, off);
    }
    if (lane == 0) { redT[w] = t_sum; redPe[w] = p_exp; redPs[w] = p_s; redC[w] = p_cnt; }
    __syncthreads();
    if (tid == 0) {
        double T = 0, Pe = 0, Ps = 0;
        long long C = 0;
        for (int i = 0; i < 8; i++) {
            T += (double)redT[i]; Pe += (double)redPe[i];
            Ps += (double)redPs[i]; C += redC[i];
        }
        double scale = (bi == bj) ? 1.0 : 2.0;   // symmetry: off-diagonal counts twice
        double* dst = partials + (size_t)swz * 8;
        dst[0] = T * scale;
        dst[1] = Pe * scale;
        dst[2] = Ps * scale;
        dst[3] = (double)C * scale;
    }
}

// ---------- finalize: reduce 528 partials, compute loss ----------
__global__ __launch_bounds__(256) void finalize_kernel(
    const double* __restrict__ partials, float* __restrict__ out) {
    const int tid = threadIdx.x;
    const int lane = tid & 63;
    const int w = tid >> 6;
    double T = 0, Pe = 0, Ps = 0, C = 0;
    for (int i = tid; i < NBLK; i += 256) {
        const double* src = partials + (size_t)i * 8;
        T += src[0]; Pe += src[1]; Ps += src[2]; C += src[3];
    }
#pragma unroll
    for (int off = 32; off > 0; off >>= 1) {
        T += __shfl_down(T, off);
        Pe += __shfl_down(Pe, off);
        Ps += __shfl_down(Ps, off);
        C += __shfl_down(C, off);
    }
    __shared__ double redT[4], redPe[4], redPs[4], redC[4];
    if (lane == 0) { redT[w] = T; redPe[w] = Pe; redPs[w] = Ps; redC[w] = C; }
    __syncthreads();
    if (tid == 0) {
        double Tt = 0, Pet = 0, Pst = 0, n = 0;
        for (int i = 0; i < 4; i++) { Tt += redT[i]; Pet += redPe[i]; Pst += redPs[i]; n += redC[i]; }
        double neg = Tt - Pet;   // negatives incl. diagonal
        double loss = (n > 0.0) ? log(neg) + (Pet / neg - Pst) / n : 0.0;
        out[0] = (float)loss;
    }
}

extern "C" void kernel_launch(void* const* d_in, const int* in_sizes, int n_in,
                              void* d_out, int out_size, void* d_ws, size_t ws_size,
                              hipStream_t stream) {
    const float* rep = (const float*)d_in[0];
    const int* codes = (const int*)d_in[1];
    // d_in[2] = labels, unused by the reference computation

    // workspace layout
    unsigned short* nb = (unsigned short*)d_ws;                // 2 MiB raw bf16
    char* p = (char*)d_ws + (size_t)B_ * D_ * 2;
    float* invs = (float*)p;                                   // 16 KiB
    u64* lo = (u64*)(invs + B_);                               // 32 KiB
    u64* hi = lo + B_;                                         // 32 KiB
    int* cnt = (int*)(hi + B_);                                // 16 KiB
    double* partials = (double*)(cnt + B_);                    // 528 x 8 doubles

    float* out = (float*)d_out;

    prep_kernel<<<B_ / 4, 256, 0, stream>>>(rep, codes, nb, invs, lo, hi, cnt);
    fused_kernel<<<NBLK, 512, 0, stream>>>(nb, invs, lo, hi, cnt, partials);
    finalize_kernel<<<1, 256, 0, stream>>>(partials, out);
}